// Round 16
// baseline (190.926 us; speedup 1.0000x reference)
//
#include <hip/hip_runtime.h>

#define Bb 4
#define Tt 2048
#define Cc 1024
#define Hh 16
#define NQKV 3072
#define Mtot 8192

typedef __bf16 bf16_t;
typedef unsigned short u16;
typedef __bf16 bf16x8 __attribute__((ext_vector_type(8)));
typedef __bf16 bf16x4 __attribute__((ext_vector_type(4)));
typedef short short4v __attribute__((ext_vector_type(4)));
typedef float f32x4 __attribute__((ext_vector_type(4)));
typedef float f32x16 __attribute__((ext_vector_type(16)));
typedef unsigned uint2v __attribute__((ext_vector_type(2)));

union bfu { bf16_t b; u16 u; };
union trpair { short4v h[2]; bf16x8 v; };
union pfu { unsigned u[4]; bf16x8 v; };

#define QSCALE 0.18033688011112042f  /* 0.125 * log2(e) */

#define TRD(dst, addr, OFF)                                                     \
  asm volatile("ds_read_b64_tr_b16 %0, %1 offset:" OFF                          \
               : "=v"(dst) : "v"(addr) : "memory")

__device__ __forceinline__ unsigned cvtpk(float a, float b) {
  unsigned r;
  asm("v_cvt_pk_bf16_f32 %0, %1, %2" : "=v"(r) : "v"(a), "v"(b));
  return r;
}
__device__ __forceinline__ uint2v plswap(unsigned a, unsigned b) {
  return __builtin_amdgcn_permlane32_swap(a, b, false, false);
}

// ---------------------------------------------------------------------------
// One-launch conversion: x, w_attn (QSCALE on q rows), w_proj -> bf16;
// b_attn -> scaled f32 bias.
// ---------------------------------------------------------------------------
__device__ __forceinline__ void cvt8(const float* s, u16* d, size_t i, float f) {
  float4 a = *(const float4*)(s + i);
  float4 b = *(const float4*)(s + i + 4);
  bf16x8 v;
  v[0]=(bf16_t)(a.x*f); v[1]=(bf16_t)(a.y*f); v[2]=(bf16_t)(a.z*f); v[3]=(bf16_t)(a.w*f);
  v[4]=(bf16_t)(b.x*f); v[5]=(bf16_t)(b.y*f); v[6]=(bf16_t)(b.z*f); v[7]=(bf16_t)(b.w*f);
  *(bf16x8*)(d + i) = v;
}

__global__ __launch_bounds__(256) void cvt_all(
    const float* __restrict__ x, const float* __restrict__ w_attn,
    const float* __restrict__ w_proj, const float* __restrict__ b_attn,
    u16* __restrict__ xb, u16* __restrict__ wab, u16* __restrict__ wpb,
    float* __restrict__ sbias)
{
  const int blk = blockIdx.x;
  if (blk < 4096) {                       // x
    size_t i = ((size_t)blk * 256 + threadIdx.x) * 8;
    cvt8(x, xb, i, 1.0f);
  } else if (blk < 5632) {                // w_attn
    size_t i = ((size_t)(blk - 4096) * 256 + threadIdx.x) * 8;
    cvt8(w_attn, wab, i, (i < (size_t)Cc * Cc) ? QSCALE : 1.0f);
  } else if (blk < 6144) {                // w_proj
    size_t i = ((size_t)(blk - 5632) * 256 + threadIdx.x) * 8;
    cvt8(w_proj, wpb, i, 1.0f);
  } else {                                // b_attn -> sbias
    int i0 = (blk - 6144) * 2048 + threadIdx.x * 8;
#pragma unroll
    for (int j = 0; j < 8; ++j) {
      int i = i0 + j;
      if (i < NQKV) sbias[i] = b_attn[i] * ((i < Cc) ? QSCALE : 1.0f);
    }
  }
}

// ---------------------------------------------------------------------------
// GEMM NT, bf16 inputs, reg-staged with preload (r4 structure — best measured)
// + T1 XCD-aware bijective block swizzle (1D grid, nwg % 8 == 0).
// Logical tile id t decomposed bm-fast (M/128 == 64): each XCD owns
// {all 64 bm} x {nwg/512 bn panels}; its B panels stay L2-resident.
// ---------------------------------------------------------------------------
template <int OUTBF16>
__global__ __launch_bounds__(256) void gemm_bf16(
    const u16* __restrict__ A, const u16* __restrict__ Bm,
    const float* __restrict__ bias, void* __restrict__ Cout,
    int M, int N, int K)
{
  __shared__ __attribute__((aligned(16))) u16 sa[128][40];
  __shared__ __attribute__((aligned(16))) u16 sb[128][40];

  const int tid  = threadIdx.x;
  const int lane = tid & 63;
  const int wid  = tid >> 6;
  const int wr   = (wid >> 1) * 64;
  const int wc   = (wid & 1) * 64;
  const int l15  = lane & 15;
  const int lh   = lane >> 4;

  // T1 swizzle: consecutive hw blocks (round-robin'd across XCDs) map to
  // strided logical tiles so each XCD gets a contiguous logical chunk.
  const int nwg   = (int)gridDim.x;       // multiple of 8
  const int chunk = nwg >> 3;
  const int t     = ((int)blockIdx.x & 7) * chunk + ((int)blockIdx.x >> 3);
  const int bm    = (t & 63) * 128;       // M/128 == 64 (bm-fast)
  const int bn    = (t >> 6) * 128;

  f32x4 acc[4][4] = {};

  const int srow = tid >> 1;
  const int sseg = (tid & 1) * 16;

  const u16* pa = A  + (size_t)(bm + srow) * K + sseg;
  const u16* pb = Bm + (size_t)(bn + srow) * K + sseg;

  uint4 ar0 = *(const uint4*)pa, ar1 = *(const uint4*)(pa + 8);
  uint4 br0 = *(const uint4*)pb, br1 = *(const uint4*)(pb + 8);
  pa += 32; pb += 32;

  for (int k0 = 0; k0 < K; k0 += 32) {
    __syncthreads();
    *(uint4*)&sa[srow][sseg]     = ar0;
    *(uint4*)&sa[srow][sseg + 8] = ar1;
    *(uint4*)&sb[srow][sseg]     = br0;
    *(uint4*)&sb[srow][sseg + 8] = br1;
    __syncthreads();
    if (k0 + 32 < K) {
      ar0 = *(const uint4*)pa; ar1 = *(const uint4*)(pa + 8);
      br0 = *(const uint4*)pb; br1 = *(const uint4*)(pb + 8);
      pa += 32; pb += 32;
    }
    bf16x8 af[4], bfv[4];
#pragma unroll
    for (int mi = 0; mi < 4; mi++)
      af[mi] = *(const bf16x8*)&sa[wr + mi*16 + l15][lh * 8];
#pragma unroll
    for (int ni = 0; ni < 4; ni++)
      bfv[ni] = *(const bf16x8*)&sb[wc + ni*16 + l15][lh * 8];
#pragma unroll
    for (int mi = 0; mi < 4; mi++)
#pragma unroll
      for (int ni = 0; ni < 4; ni++)
        acc[mi][ni] = __builtin_amdgcn_mfma_f32_16x16x32_bf16(
            af[mi], bfv[ni], acc[mi][ni], 0, 0, 0);
  }

#pragma unroll
  for (int mi = 0; mi < 4; mi++) {
#pragma unroll
    for (int ni = 0; ni < 4; ni++) {
      const int col = bn + wc + ni*16 + l15;
      const float bs = bias[col];
#pragma unroll
      for (int r = 0; r < 4; r++) {
        const int row = bm + wr + mi*16 + lh*4 + r;
        const float val = acc[mi][ni][r] + bs;
        if (OUTBF16) {
          bfu cv; cv.b = (bf16_t)val;
          ((u16*)Cout)[(size_t)row * N + col] = cv.u;
        } else {
          ((float*)Cout)[(size_t)row * N + col] = val;
        }
      }
    }
  }
}

// ---------------------------------------------------------------------------
// Causal flash attention (r11 version, unchanged — 81.7 us measured):
// 8-wave blocks, 256-row q-tiles paired {x,7-x}; 3-buffer K/V rotation, one
// barrier per tile; T15 qk-ahead; T12 in-register softmax; tr-read PV.
// ---------------------------------------------------------------------------
#define BUFU 9216   /* u16 per buffer */

__global__ __launch_bounds__(512) void attn_kernel(
    const u16* __restrict__ qkv, u16* __restrict__ y)
{
  __shared__ __attribute__((aligned(16))) u16 smem[3 * BUFU];  // 55.3 KB

  const int tid  = threadIdx.x;
  const int lane = tid & 63;
  const int w    = tid >> 6;          // 0..7
  const int l31  = lane & 31;
  const int hh   = lane >> 5;
  const int l15  = lane & 15;
  const int lh   = lane >> 4;
  const int bh   = blockIdx.y;
  const int b    = bh >> 4;
  const int head = bh & 15;

  const size_t rowbase = (size_t)b * Tt * NQKV;

  const int skey = tid >> 3;
  const int sp   = tid & 7;
  const u16* kbase = qkv + rowbase + 1024 + head*64 + sp*8;
  const u16* vbase = qkv + rowbase + 2048 + head*64 + sp*8;

  const unsigned smemB = (unsigned)(size_t)(&smem[0]);
  const unsigned trl = smemB
      + ((lh>>1)*8 + (l15>>2))*144 + (lh&1)*32 + (l15&3)*8;

  uint4 kr0, vr0;
#define LOADREGS(t) do {                                                        \
    kr0 = *(const uint4*)(kbase + (size_t)((t)*64 + skey) * NQKV);              \
    vr0 = *(const uint4*)(vbase + (size_t)((t)*64 + skey) * NQKV);              \
  } while (0)
#define STAGEB(bofs) do {                                                       \
    *(uint4*)&smem[(bofs) + skey*72 + sp*8]        = kr0;                       \
    *(uint4*)&smem[(bofs) + 4608 + skey*72 + sp*8] = vr0;                       \
  } while (0)

  for (int half = 0; half < 2; ++half) {
    const int qx    = half ? (7 - (int)blockIdx.x) : (int)blockIdx.x;
    const int qbase = qx * 256;
    const int qw    = qbase + w * 32;
    const int qi    = qw + l31;
    const int ktiles = 4*qx + 4;

    bf16x8 qfrag[4];
#pragma unroll
    for (int m = 0; m < 4; ++m)
      qfrag[m] = *(const bf16x8*)(qkv + rowbase + (size_t)qi * NQKV
                                  + head*64 + m*16 + hh*8);

    f32x16 o0 = {}, o1 = {};
    float m_run = -1e30f, l_part = 0.0f;
    f32x16 sA0, sA1, sB0, sB1;

    auto qk = [&](f32x16& t0, f32x16& t1, int kofs, int kb0) {
      f32x16 a0 = {}, a1 = {};
      __builtin_amdgcn_s_setprio(1);
#pragma unroll
      for (int m = 0; m < 4; ++m) {
        const int co = m*16 + hh*8;
        bf16x8 k0 = *(const bf16x8*)&smem[kofs + l31*72 + co];
        bf16x8 k1 = *(const bf16x8*)&smem[kofs + (32 + l31)*72 + co];
        a0 = __builtin_amdgcn_mfma_f32_32x32x16_bf16(k0, qfrag[m], a0, 0,0,0);
        a1 = __builtin_amdgcn_mfma_f32_32x32x16_bf16(k1, qfrag[m], a1, 0,0,0);
      }
      __builtin_amdgcn_s_setprio(0);
      if (kb0 + 63 > qw) {
#pragma unroll
        for (int r = 0; r < 16; ++r) {
          const int crow = (r&3) + 8*(r>>2) + 4*hh;
          if (kb0 + crow > qi)      a0[r] = -1e30f;
          if (kb0 + 32 + crow > qi) a1[r] = -1e30f;
        }
      }
      t0 = a0; t1 = a1;
    };

    auto smpv = [&](f32x16& s0, f32x16& s1, int bofs) {
      float mx[8];
#pragma unroll
      for (int i = 0; i < 8; ++i)
        mx[i] = fmaxf(fmaxf(s0[i], s0[i+8]), fmaxf(s1[i], s1[i+8]));
#pragma unroll
      for (int i = 0; i < 4; ++i) mx[i] = fmaxf(mx[i], mx[i+4]);
      mx[0] = fmaxf(mx[0], mx[2]); mx[1] = fmaxf(mx[1], mx[3]);
      float rm = fmaxf(mx[0], mx[1]);
      {
        uint2v t = plswap(__float_as_uint(rm), __float_as_uint(rm));
        rm = fmaxf(__uint_as_float(t[0]), __uint_as_float(t[1]));
      }
      if (__any(rm > m_run + 8.0f)) {
        const float mn = fmaxf(m_run, rm);
        const float al = exp2f(m_run - mn);
        m_run = mn; l_part *= al;
#pragma unroll
        for (int r = 0; r < 16; ++r) { o0[r] *= al; o1[r] *= al; }
      }

      pfu pf0, pf1, pf2, pf3;
      float lp0 = 0.f, lp1 = 0.f, lp2 = 0.f, lp3 = 0.f;
      {
        float pe[16];
#pragma unroll
        for (int r = 0; r < 16; ++r) pe[r] = exp2f(s0[r] - m_run);
#pragma unroll
        for (int r = 0; r < 4; ++r) {
          lp0 += pe[r]; lp1 += pe[4+r]; lp2 += pe[8+r]; lp3 += pe[12+r];
        }
        unsigned a0 = cvtpk(pe[0],pe[1]),  a1 = cvtpk(pe[2],pe[3]);
        unsigned a2 = cvtpk(pe[4],pe[5]),  a3 = cvtpk(pe[6],pe[7]);
        uint2v x1 = plswap(a0, a2), x2 = plswap(a1, a3);
        pf0.u[0]=x1[0]; pf0.u[1]=x2[0]; pf0.u[2]=x1[1]; pf0.u[3]=x2[1];
        unsigned b0 = cvtpk(pe[8],pe[9]),  b1 = cvtpk(pe[10],pe[11]);
        unsigned b2 = cvtpk(pe[12],pe[13]), b3 = cvtpk(pe[14],pe[15]);
        uint2v x3 = plswap(b0, b2), x4 = plswap(b1, b3);
        pf1.u[0]=x3[0]; pf1.u[1]=x4[0]; pf1.u[2]=x3[1]; pf1.u[3]=x4[1];
      }
      {
        float pe[16];
#pragma unroll
        for (int r = 0; r < 16; ++r) pe[r] = exp2f(s1[r] - m_run);
#pragma unroll
        for (int r = 0; r < 4; ++r) {
          lp0 += pe[r]; lp1 += pe[4+r]; lp2 += pe[8+r]; lp3 += pe[12+r];
        }
        unsigned a0 = cvtpk(pe[0],pe[1]),  a1 = cvtpk(pe[2],pe[3]);
        unsigned a2 = cvtpk(pe[4],pe[5]),  a3 = cvtpk(pe[6],pe[7]);
        uint2v x1 = plswap(a0, a2), x2 = plswap(a1, a3);
        pf2.u[0]=x1[0]; pf2.u[1]=x2[0]; pf2.u[2]=x1[1]; pf2.u[3]=x2[1];
        unsigned b0 = cvtpk(pe[8],pe[9]),  b1 = cvtpk(pe[10],pe[11]);
        unsigned b2 = cvtpk(pe[12],pe[13]), b3 = cvtpk(pe[14],pe[15]);
        uint2v x3 = plswap(b0, b2), x4 = plswap(b1, b3);
        pf3.u[0]=x3[0]; pf3.u[1]=x4[0]; pf3.u[2]=x3[1]; pf3.u[3]=x4[1];
      }
      l_part += (lp0 + lp1) + (lp2 + lp3);

      const unsigned va = trl + (unsigned)(bofs*2 + 9216);
      short4v ta0,tb0,ta1,tb1,ta2,tb2,ta3,tb3,ta4,tb4,ta5,tb5,ta6,tb6,ta7,tb7;
      TRD(ta0, va, "0");    TRD(tb0, va, "576");
      TRD(ta1, va, "64");   TRD(tb1, va, "640");
      TRD(ta2, va, "2304"); TRD(tb2, va, "2880");
      TRD(ta3, va, "2368"); TRD(tb3, va, "2944");
      TRD(ta4, va, "4608"); TRD(tb4, va, "5184");
      TRD(ta5, va, "4672"); TRD(tb5, va, "5248");
      TRD(ta6, va, "6912"); TRD(tb6, va, "7488");
      TRD(ta7, va, "6976"); TRD(tb7, va, "7552");
      asm volatile("s_waitcnt lgkmcnt(0)" ::: "memory");
      __builtin_amdgcn_sched_barrier(0);
      trpair v00,v01,v10,v11,v20,v21,v30,v31;
      v00.h[0]=ta0; v00.h[1]=tb0;  v01.h[0]=ta1; v01.h[1]=tb1;
      v10.h[0]=ta2; v10.h[1]=tb2;  v11.h[0]=ta3; v11.h[1]=tb3;
      v20.h[0]=ta4; v20.h[1]=tb4;  v21.h[0]=ta5; v21.h[1]=tb5;
      v30.h[0]=ta6; v30.h[1]=tb6;  v31.h[0]=ta7; v31.h[1]=tb7;
      __builtin_amdgcn_s_setprio(1);
      o0 = __builtin_amdgcn_mfma_f32_32x32x16_bf16(v00.v, pf0.v, o0, 0,0,0);
      o1 = __builtin_amdgcn_mfma_f32_32x32x16_bf16(v01.v, pf0.v, o1, 0,0,0);
      o0 = __builtin_amdgcn_mfma_f32_32x32x16_bf16(v10.v, pf1.v, o0, 0,0,0);
      o1 = __builtin_amdgcn_mfma_f32_32x32x16_bf16(v11.v, pf1.v, o1, 0,0,0);
      o0 = __builtin_amdgcn_mfma_f32_32x32x16_bf16(v20.v, pf2.v, o0, 0,0,0);
      o1 = __builtin_amdgcn_mfma_f32_32x32x16_bf16(v21.v, pf2.v, o1, 0,0,0);
      o0 = __builtin_amdgcn_mfma_f32_32x32x16_bf16(v30.v, pf3.v, o0, 0,0,0);
      o1 = __builtin_amdgcn_mfma_f32_32x32x16_bf16(v31.v, pf3.v, o1, 0,0,0);
      __builtin_amdgcn_s_setprio(0);
    };

    LOADREGS(0);
    __syncthreads();
    STAGEB(0);
    LOADREGS(1);
    __syncthreads();
    qk(sA0, sA1, 0, 0);
    STAGEB(BUFU);
    LOADREGS(2);

    int cofs = 0, nofs = BUFU, fofs = 2*BUFU;

    for (int kt = 0; kt < ktiles; kt += 2) {
      __syncthreads();
      if ((kt+1)*64 <= qw + 31) qk(sB0, sB1, nofs, (kt+1)*64);
      if (kt*64 <= qw + 31)     smpv(sA0, sA1, cofs);
      if (kt + 2 < ktiles) {
        STAGEB(fofs);
        if (kt + 3 < ktiles) LOADREGS(kt + 3);
      }
      { int t = cofs; cofs = nofs; nofs = fofs; fofs = t; }

      __syncthreads();
      if ((kt+2) < ktiles && (kt+2)*64 <= qw + 31) qk(sA0, sA1, nofs, (kt+2)*64);
      if ((kt+1)*64 <= qw + 31) smpv(sB0, sB1, cofs);
      if (kt + 3 < ktiles) {
        STAGEB(fofs);
        if (kt + 4 < ktiles) LOADREGS(kt + 4);
      }
      { int t = cofs; cofs = nofs; nofs = fofs; fofs = t; }
    }

    {
      uint2v t = plswap(__float_as_uint(l_part), __float_as_uint(l_part));
      l_part = __uint_as_float(t[0]) + __uint_as_float(t[1]);
    }
    const float inv = 1.0f / l_part;

    __syncthreads();
#pragma unroll
    for (int k4 = 0; k4 < 4; ++k4) {
      bf16x4 pa, pb;
#pragma unroll
      for (int j = 0; j < 4; ++j) {
        pa[j] = (bf16_t)(o0[4*k4 + j] * inv);
        pb[j] = (bf16_t)(o1[4*k4 + j] * inv);
      }
      *(bf16x4*)&smem[w*2304 + l31*72 +      8*k4 + 4*hh] = pa;
      *(bf16x4*)&smem[w*2304 + l31*72 + 32 + 8*k4 + 4*hh] = pb;
    }
    u16* yp = y + ((size_t)(b*Tt + qi)) * Cc + head*64;
#pragma unroll
    for (int p = 0; p < 4; ++p) {
      bf16x8 row = *(const bf16x8*)&smem[w*2304 + l31*72 + p*16 + hh*8];
      *(bf16x8*)(yp + p*16 + hh*8) = row;
    }
  }
#undef LOADREGS
#undef STAGEB
}

// ---------------------------------------------------------------------------
extern "C" void kernel_launch(void* const* d_in, const int* in_sizes, int n_in,
                              void* d_out, int out_size, void* d_ws, size_t ws_size,
                              hipStream_t stream) {
  const float* x      = (const float*)d_in[0];
  const float* w_attn = (const float*)d_in[1];
  const float* b_attn = (const float*)d_in[2];
  const float* w_proj = (const float*)d_in[3];
  const float* b_proj = (const float*)d_in[4];
  float* out = (float*)d_out;

  char* ws = (char*)d_ws;
  u16*   xb    = (u16*)(ws + 0);          // 16 MB
  u16*   wab   = (u16*)(ws + 16777216);   // 6 MB
  u16*   wpb   = (u16*)(ws + 23068672);   // 2 MB
  u16*   qkvb  = (u16*)(ws + 25165824);   // 48 MB
  u16*   yb    = (u16*)(ws + 75497472);   // 16 MB
  float* sbias = (float*)(ws + 92274688); // 12 KB

  // single-launch conversion (x, w_attn+QSCALE, w_proj, b_attn)
  cvt_all<<<6146, 256, 0, stream>>>(x, w_attn, w_proj, b_attn,
                                    xb, wab, wpb, sbias);

  // 1) QKV projection (bf16 out) — 128^2 reg-staged + XCD swizzle (1536 blocks)
  gemm_bf16<1><<<(Mtot/128) * (NQKV/128), 256, 0, stream>>>(
      xb, wab, sbias, (void*)qkvb, Mtot, NQKV, Cc);

  // 2) causal attention (bf16 y)
  attn_kernel<<<dim3(4, Bb*Hh), 512, 0, stream>>>(qkvb, yb);

  // 3) output projection (f32 out) — + XCD swizzle (512 blocks)
  gemm_bf16<0><<<(Mtot/128) * (Cc/128), 256, 0, stream>>>(
      yb, wpb, b_proj, (void*)out, Mtot, Cc, Cc);
}

// Round 17
// 181.697 us; speedup vs baseline: 1.0508x; 1.0508x over previous
//
#include <hip/hip_runtime.h>

#define Bb 4
#define Tt 2048
#define Cc 1024
#define Hh 16
#define NQKV 3072
#define Mtot 8192

typedef __bf16 bf16_t;
typedef unsigned short u16;
typedef __bf16 bf16x8 __attribute__((ext_vector_type(8)));
typedef __bf16 bf16x4 __attribute__((ext_vector_type(4)));
typedef short short4v __attribute__((ext_vector_type(4)));
typedef float f32x4 __attribute__((ext_vector_type(4)));
typedef float f32x16 __attribute__((ext_vector_type(16)));
typedef unsigned uint2v __attribute__((ext_vector_type(2)));

union bfu { bf16_t b; u16 u; };
union trpair { short4v h[2]; bf16x8 v; };
union pfu { unsigned u[4]; bf16x8 v; };

#define QSCALE 0.18033688011112042f  /* 0.125 * log2(e) */

// hardware transpose read; "memory" clobber keeps it ordered vs ds_writes
#define TRD(dst, addr, OFF)                                                     \
  asm volatile("ds_read_b64_tr_b16 %0, %1 offset:" OFF                          \
               : "=v"(dst) : "v"(addr) : "memory")

__device__ __forceinline__ unsigned cvtpk(float a, float b) {
  unsigned r;
  asm("v_cvt_pk_bf16_f32 %0, %1, %2" : "=v"(r) : "v"(a), "v"(b));
  return r;
}
__device__ __forceinline__ uint2v plswap(unsigned a, unsigned b) {
  return __builtin_amdgcn_permlane32_swap(a, b, false, false);
}

// ---------------------------------------------------------------------------
// One-launch conversion: x, w_attn (QSCALE on q rows), w_proj -> bf16;
// b_attn -> scaled f32 bias.
// ---------------------------------------------------------------------------
__device__ __forceinline__ void cvt8(const float* s, u16* d, size_t i, float f) {
  float4 a = *(const float4*)(s + i);
  float4 b = *(const float4*)(s + i + 4);
  bf16x8 v;
  v[0]=(bf16_t)(a.x*f); v[1]=(bf16_t)(a.y*f); v[2]=(bf16_t)(a.z*f); v[3]=(bf16_t)(a.w*f);
  v[4]=(bf16_t)(b.x*f); v[5]=(bf16_t)(b.y*f); v[6]=(bf16_t)(b.z*f); v[7]=(bf16_t)(b.w*f);
  *(bf16x8*)(d + i) = v;
}

__global__ __launch_bounds__(256) void cvt_all(
    const float* __restrict__ x, const float* __restrict__ w_attn,
    const float* __restrict__ w_proj, const float* __restrict__ b_attn,
    u16* __restrict__ xb, u16* __restrict__ wab, u16* __restrict__ wpb,
    float* __restrict__ sbias)
{
  const int blk = blockIdx.x;
  if (blk < 4096) {                       // x
    size_t i = ((size_t)blk * 256 + threadIdx.x) * 8;
    cvt8(x, xb, i, 1.0f);
  } else if (blk < 5632) {                // w_attn
    size_t i = ((size_t)(blk - 4096) * 256 + threadIdx.x) * 8;
    cvt8(w_attn, wab, i, (i < (size_t)Cc * Cc) ? QSCALE : 1.0f);
  } else if (blk < 6144) {                // w_proj
    size_t i = ((size_t)(blk - 5632) * 256 + threadIdx.x) * 8;
    cvt8(w_proj, wpb, i, 1.0f);
  } else {                                // b_attn -> sbias
    int i0 = (blk - 6144) * 2048 + threadIdx.x * 8;
#pragma unroll
    for (int j = 0; j < 8; ++j) {
      int i = i0 + j;
      if (i < NQKV) sbias[i] = b_attn[i] * ((i < Cc) ? QSCALE : 1.0f);
    }
  }
}

// ---------------------------------------------------------------------------
// GEMM NT, bf16 inputs, reg-staged with preload (r4 version — fastest measured)
// ---------------------------------------------------------------------------
template <int OUTBF16>
__global__ __launch_bounds__(256) void gemm_bf16(
    const u16* __restrict__ A, const u16* __restrict__ Bm,
    const float* __restrict__ bias, void* __restrict__ Cout,
    int M, int N, int K)
{
  __shared__ __attribute__((aligned(16))) u16 sa[128][40];
  __shared__ __attribute__((aligned(16))) u16 sb[128][40];

  const int tid  = threadIdx.x;
  const int lane = tid & 63;
  const int wid  = tid >> 6;
  const int wr   = (wid >> 1) * 64;
  const int wc   = (wid & 1) * 64;
  const int l15  = lane & 15;
  const int lh   = lane >> 4;
  const int bm   = blockIdx.x * 128;
  const int bn   = blockIdx.y * 128;

  f32x4 acc[4][4] = {};

  const int srow = tid >> 1;
  const int sseg = (tid & 1) * 16;

  const u16* pa = A  + (size_t)(bm + srow) * K + sseg;
  const u16* pb = Bm + (size_t)(bn + srow) * K + sseg;

  uint4 ar0 = *(const uint4*)pa, ar1 = *(const uint4*)(pa + 8);
  uint4 br0 = *(const uint4*)pb, br1 = *(const uint4*)(pb + 8);
  pa += 32; pb += 32;

  for (int k0 = 0; k0 < K; k0 += 32) {
    __syncthreads();
    *(uint4*)&sa[srow][sseg]     = ar0;
    *(uint4*)&sa[srow][sseg + 8] = ar1;
    *(uint4*)&sb[srow][sseg]     = br0;
    *(uint4*)&sb[srow][sseg + 8] = br1;
    __syncthreads();
    if (k0 + 32 < K) {
      ar0 = *(const uint4*)pa; ar1 = *(const uint4*)(pa + 8);
      br0 = *(const uint4*)pb; br1 = *(const uint4*)(pb + 8);
      pa += 32; pb += 32;
    }
    bf16x8 af[4], bfv[4];
#pragma unroll
    for (int mi = 0; mi < 4; mi++)
      af[mi] = *(const bf16x8*)&sa[wr + mi*16 + l15][lh * 8];
#pragma unroll
    for (int ni = 0; ni < 4; ni++)
      bfv[ni] = *(const bf16x8*)&sb[wc + ni*16 + l15][lh * 8];
#pragma unroll
    for (int mi = 0; mi < 4; mi++)
#pragma unroll
      for (int ni = 0; ni < 4; ni++)
        acc[mi][ni] = __builtin_amdgcn_mfma_f32_16x16x32_bf16(
            af[mi], bfv[ni], acc[mi][ni], 0, 0, 0);
  }

#pragma unroll
  for (int mi = 0; mi < 4; mi++) {
#pragma unroll
    for (int ni = 0; ni < 4; ni++) {
      const int col = bn + wc + ni*16 + l15;
      const float bs = bias[col];
#pragma unroll
      for (int r = 0; r < 4; r++) {
        const int row = bm + wr + mi*16 + lh*4 + r;
        const float val = acc[mi][ni][r] + bs;
        if (OUTBF16) {
          bfu cv; cv.b = (bf16_t)val;
          ((u16*)Cout)[(size_t)row * N + col] = cv.u;
        } else {
          ((float*)Cout)[(size_t)row * N + col] = val;
        }
      }
    }
  }
}

// ---------------------------------------------------------------------------
// Causal flash attention (r11 version — 81.7 us measured): 8-wave blocks,
// 256-row q-tiles paired {x,7-x}; 3-buffer K/V rotation, one barrier per
// tile; T15 qk-ahead; T12 in-register softmax; tr-read PV.
// ---------------------------------------------------------------------------
#define BUFU 9216   /* u16 per buffer */

__global__ __launch_bounds__(512) void attn_kernel(
    const u16* __restrict__ qkv, u16* __restrict__ y)
{
  __shared__ __attribute__((aligned(16))) u16 smem[3 * BUFU];  // 55.3 KB

  const int tid  = threadIdx.x;
  const int lane = tid & 63;
  const int w    = tid >> 6;          // 0..7
  const int l31  = lane & 31;
  const int hh   = lane >> 5;
  const int l15  = lane & 15;
  const int lh   = lane >> 4;
  const int bh   = blockIdx.y;
  const int b    = bh >> 4;
  const int head = bh & 15;

  const size_t rowbase = (size_t)b * Tt * NQKV;

  const int skey = tid >> 3;
  const int sp   = tid & 7;
  const u16* kbase = qkv + rowbase + 1024 + head*64 + sp*8;
  const u16* vbase = qkv + rowbase + 2048 + head*64 + sp*8;

  const unsigned smemB = (unsigned)(size_t)(&smem[0]);
  const unsigned trl = smemB
      + ((lh>>1)*8 + (l15>>2))*144 + (lh&1)*32 + (l15&3)*8;

  uint4 kr0, vr0;
#define LOADREGS(t) do {                                                        \
    kr0 = *(const uint4*)(kbase + (size_t)((t)*64 + skey) * NQKV);              \
    vr0 = *(const uint4*)(vbase + (size_t)((t)*64 + skey) * NQKV);              \
  } while (0)
#define STAGEB(bofs) do {                                                       \
    *(uint4*)&smem[(bofs) + skey*72 + sp*8]        = kr0;                       \
    *(uint4*)&smem[(bofs) + 4608 + skey*72 + sp*8] = vr0;                       \
  } while (0)

  for (int half = 0; half < 2; ++half) {
    const int qx    = half ? (7 - (int)blockIdx.x) : (int)blockIdx.x;
    const int qbase = qx * 256;
    const int qw    = qbase + w * 32;
    const int qi    = qw + l31;
    const int ktiles = 4*qx + 4;

    bf16x8 qfrag[4];
#pragma unroll
    for (int m = 0; m < 4; ++m)
      qfrag[m] = *(const bf16x8*)(qkv + rowbase + (size_t)qi * NQKV
                                  + head*64 + m*16 + hh*8);

    f32x16 o0 = {}, o1 = {};
    float m_run = -1e30f, l_part = 0.0f;
    f32x16 sA0, sA1, sB0, sB1;

    auto qk = [&](f32x16& t0, f32x16& t1, int kofs, int kb0) {
      f32x16 a0 = {}, a1 = {};
      __builtin_amdgcn_s_setprio(1);
#pragma unroll
      for (int m = 0; m < 4; ++m) {
        const int co = m*16 + hh*8;
        bf16x8 k0 = *(const bf16x8*)&smem[kofs + l31*72 + co];
        bf16x8 k1 = *(const bf16x8*)&smem[kofs + (32 + l31)*72 + co];
        a0 = __builtin_amdgcn_mfma_f32_32x32x16_bf16(k0, qfrag[m], a0, 0,0,0);
        a1 = __builtin_amdgcn_mfma_f32_32x32x16_bf16(k1, qfrag[m], a1, 0,0,0);
      }
      __builtin_amdgcn_s_setprio(0);
      if (kb0 + 63 > qw) {
#pragma unroll
        for (int r = 0; r < 16; ++r) {
          const int crow = (r&3) + 8*(r>>2) + 4*hh;
          if (kb0 + crow > qi)      a0[r] = -1e30f;
          if (kb0 + 32 + crow > qi) a1[r] = -1e30f;
        }
      }
      t0 = a0; t1 = a1;
    };

    auto smpv = [&](f32x16& s0, f32x16& s1, int bofs) {
      float mx[8];
#pragma unroll
      for (int i = 0; i < 8; ++i)
        mx[i] = fmaxf(fmaxf(s0[i], s0[i+8]), fmaxf(s1[i], s1[i+8]));
#pragma unroll
      for (int i = 0; i < 4; ++i) mx[i] = fmaxf(mx[i], mx[i+4]);
      mx[0] = fmaxf(mx[0], mx[2]); mx[1] = fmaxf(mx[1], mx[3]);
      float rm = fmaxf(mx[0], mx[1]);
      {
        uint2v t = plswap(__float_as_uint(rm), __float_as_uint(rm));
        rm = fmaxf(__uint_as_float(t[0]), __uint_as_float(t[1]));
      }
      if (__any(rm > m_run + 8.0f)) {
        const float mn = fmaxf(m_run, rm);
        const float al = exp2f(m_run - mn);
        m_run = mn; l_part *= al;
#pragma unroll
        for (int r = 0; r < 16; ++r) { o0[r] *= al; o1[r] *= al; }
      }

      pfu pf0, pf1, pf2, pf3;
      float lp0 = 0.f, lp1 = 0.f, lp2 = 0.f, lp3 = 0.f;
      {
        float pe[16];
#pragma unroll
        for (int r = 0; r < 16; ++r) pe[r] = exp2f(s0[r] - m_run);
#pragma unroll
        for (int r = 0; r < 4; ++r) {
          lp0 += pe[r]; lp1 += pe[4+r]; lp2 += pe[8+r]; lp3 += pe[12+r];
        }
        unsigned a0 = cvtpk(pe[0],pe[1]),  a1 = cvtpk(pe[2],pe[3]);
        unsigned a2 = cvtpk(pe[4],pe[5]),  a3 = cvtpk(pe[6],pe[7]);
        uint2v x1 = plswap(a0, a2), x2 = plswap(a1, a3);
        pf0.u[0]=x1[0]; pf0.u[1]=x2[0]; pf0.u[2]=x1[1]; pf0.u[3]=x2[1];
        unsigned b0 = cvtpk(pe[8],pe[9]),  b1 = cvtpk(pe[10],pe[11]);
        unsigned b2 = cvtpk(pe[12],pe[13]), b3 = cvtpk(pe[14],pe[15]);
        uint2v x3 = plswap(b0, b2), x4 = plswap(b1, b3);
        pf1.u[0]=x3[0]; pf1.u[1]=x4[0]; pf1.u[2]=x3[1]; pf1.u[3]=x4[1];
      }
      {
        float pe[16];
#pragma unroll
        for (int r = 0; r < 16; ++r) pe[r] = exp2f(s1[r] - m_run);
#pragma unroll
        for (int r = 0; r < 4; ++r) {
          lp0 += pe[r]; lp1 += pe[4+r]; lp2 += pe[8+r]; lp3 += pe[12+r];
        }
        unsigned a0 = cvtpk(pe[0],pe[1]),  a1 = cvtpk(pe[2],pe[3]);
        unsigned a2 = cvtpk(pe[4],pe[5]),  a3 = cvtpk(pe[6],pe[7]);
        uint2v x1 = plswap(a0, a2), x2 = plswap(a1, a3);
        pf2.u[0]=x1[0]; pf2.u[1]=x2[0]; pf2.u[2]=x1[1]; pf2.u[3]=x2[1];
        unsigned b0 = cvtpk(pe[8],pe[9]),  b1 = cvtpk(pe[10],pe[11]);
        unsigned b2 = cvtpk(pe[12],pe[13]), b3 = cvtpk(pe[14],pe[15]);
        uint2v x3 = plswap(b0, b2), x4 = plswap(b1, b3);
        pf3.u[0]=x3[0]; pf3.u[1]=x4[0]; pf3.u[2]=x3[1]; pf3.u[3]=x4[1];
      }
      l_part += (lp0 + lp1) + (lp2 + lp3);

      const unsigned va = trl + (unsigned)(bofs*2 + 9216);
      short4v ta0,tb0,ta1,tb1,ta2,tb2,ta3,tb3,ta4,tb4,ta5,tb5,ta6,tb6,ta7,tb7;
      TRD(ta0, va, "0");    TRD(tb0, va, "576");
      TRD(ta1, va, "64");   TRD(tb1, va, "640");
      TRD(ta2, va, "2304"); TRD(tb2, va, "2880");
      TRD(ta3, va, "2368"); TRD(tb3, va, "2944");
      TRD(ta4, va, "4608"); TRD(tb4, va, "5184");
      TRD(ta5, va, "4672"); TRD(tb5, va, "5248");
      TRD(ta6, va, "6912"); TRD(tb6, va, "7488");
      TRD(ta7, va, "6976"); TRD(tb7, va, "7552");
      asm volatile("s_waitcnt lgkmcnt(0)" ::: "memory");
      __builtin_amdgcn_sched_barrier(0);
      trpair v00,v01,v10,v11,v20,v21,v30,v31;
      v00.h[0]=ta0; v00.h[1]=tb0;  v01.h[0]=ta1; v01.h[1]=tb1;
      v10.h[0]=ta2; v10.h[1]=tb2;  v11.h[0]=ta3; v11.h[1]=tb3;
      v20.h[0]=ta4; v20.h[1]=tb4;  v21.h[0]=ta5; v21.h[1]=tb5;
      v30.h[0]=ta6; v30.h[1]=tb6;  v31.h[0]=ta7; v31.h[1]=tb7;
      __builtin_amdgcn_s_setprio(1);
      o0 = __builtin_amdgcn_mfma_f32_32x32x16_bf16(v00.v, pf0.v, o0, 0,0,0);
      o1 = __builtin_amdgcn_mfma_f32_32x32x16_bf16(v01.v, pf0.v, o1, 0,0,0);
      o0 = __builtin_amdgcn_mfma_f32_32x32x16_bf16(v10.v, pf1.v, o0, 0,0,0);
      o1 = __builtin_amdgcn_mfma_f32_32x32x16_bf16(v11.v, pf1.v, o1, 0,0,0);
      o0 = __builtin_amdgcn_mfma_f32_32x32x16_bf16(v20.v, pf2.v, o0, 0,0,0);
      o1 = __builtin_amdgcn_mfma_f32_32x32x16_bf16(v21.v, pf2.v, o1, 0,0,0);
      o0 = __builtin_amdgcn_mfma_f32_32x32x16_bf16(v30.v, pf3.v, o0, 0,0,0);
      o1 = __builtin_amdgcn_mfma_f32_32x32x16_bf16(v31.v, pf3.v, o1, 0,0,0);
      __builtin_amdgcn_s_setprio(0);
    };

    LOADREGS(0);
    __syncthreads();
    STAGEB(0);
    LOADREGS(1);
    __syncthreads();
    qk(sA0, sA1, 0, 0);
    STAGEB(BUFU);
    LOADREGS(2);

    int cofs = 0, nofs = BUFU, fofs = 2*BUFU;

    for (int kt = 0; kt < ktiles; kt += 2) {
      __syncthreads();
      if ((kt+1)*64 <= qw + 31) qk(sB0, sB1, nofs, (kt+1)*64);
      if (kt*64 <= qw + 31)     smpv(sA0, sA1, cofs);
      if (kt + 2 < ktiles) {
        STAGEB(fofs);
        if (kt + 3 < ktiles) LOADREGS(kt + 3);
      }
      { int t = cofs; cofs = nofs; nofs = fofs; fofs = t; }

      __syncthreads();
      if ((kt+2) < ktiles && (kt+2)*64 <= qw + 31) qk(sA0, sA1, nofs, (kt+2)*64);
      if ((kt+1)*64 <= qw + 31) smpv(sB0, sB1, cofs);
      if (kt + 3 < ktiles) {
        STAGEB(fofs);
        if (kt + 4 < ktiles) LOADREGS(kt + 4);
      }
      { int t = cofs; cofs = nofs; nofs = fofs; fofs = t; }
    }

    {
      uint2v t = plswap(__float_as_uint(l_part), __float_as_uint(l_part));
      l_part = __uint_as_float(t[0]) + __uint_as_float(t[1]);
    }
    const float inv = 1.0f / l_part;

    __syncthreads();
#pragma unroll
    for (int k4 = 0; k4 < 4; ++k4) {
      bf16x4 pa, pb;
#pragma unroll
      for (int j = 0; j < 4; ++j) {
        pa[j] = (bf16_t)(o0[4*k4 + j] * inv);
        pb[j] = (bf16_t)(o1[4*k4 + j] * inv);
      }
      *(bf16x4*)&smem[w*2304 + l31*72 +      8*k4 + 4*hh] = pa;
      *(bf16x4*)&smem[w*2304 + l31*72 + 32 + 8*k4 + 4*hh] = pb;
    }
    u16* yp = y + ((size_t)(b*Tt + qi)) * Cc + head*64;
#pragma unroll
    for (int p = 0; p < 4; ++p) {
      bf16x8 row = *(const bf16x8*)&smem[w*2304 + l31*72 + p*16 + hh*8];
      *(bf16x8*)(yp + p*16 + hh*8) = row;
    }
  }
#undef LOADREGS
#undef STAGEB
}

// ---------------------------------------------------------------------------
extern "C" void kernel_launch(void* const* d_in, const int* in_sizes, int n_in,
                              void* d_out, int out_size, void* d_ws, size_t ws_size,
                              hipStream_t stream) {
  const float* x      = (const float*)d_in[0];
  const float* w_attn = (const float*)d_in[1];
  const float* b_attn = (const float*)d_in[2];
  const float* w_proj = (const float*)d_in[3];
  const float* b_proj = (const float*)d_in[4];
  float* out = (float*)d_out;

  char* ws = (char*)d_ws;
  u16*   xb    = (u16*)(ws + 0);          // 16 MB
  u16*   wab   = (u16*)(ws + 16777216);   // 6 MB
  u16*   wpb   = (u16*)(ws + 23068672);   // 2 MB
  u16*   qkvb  = (u16*)(ws + 25165824);   // 48 MB
  u16*   yb    = (u16*)(ws + 75497472);   // 16 MB
  float* sbias = (float*)(ws + 92274688); // 12 KB

  // single-launch conversion (x, w_attn+QSCALE, w_proj, b_attn)
  cvt_all<<<6146, 256, 0, stream>>>(x, w_attn, w_proj, b_attn,
                                    xb, wab, wpb, sbias);

  // 1) QKV projection (bf16 out, q pre-scaled)
  gemm_bf16<1><<<dim3(Mtot/128, NQKV/128), 256, 0, stream>>>(
      xb, wab, sbias, (void*)qkvb, Mtot, NQKV, Cc);

  // 2) causal attention (bf16 y)
  attn_kernel<<<dim3(4, Bb*Hh), 512, 0, stream>>>(qkvb, yb);

  // 3) output projection (f32 out)
  gemm_bf16<0><<<dim3(Mtot/128, Cc/128), 256, 0, stream>>>(
      yb, wpb, b_proj, (void*)out, Mtot, Cc, Cc);
}

// Round 18
// 176.762 us; speedup vs baseline: 1.0801x; 1.0279x over previous
//
#include <hip/hip_runtime.h>

#define Bb 4
#define Tt 2048
#define Cc 1024
#define Hh 16
#define NQKV 3072
#define Mtot 8192

typedef __bf16 bf16_t;
typedef unsigned short u16;
typedef __bf16 bf16x8 __attribute__((ext_vector_type(8)));
typedef __bf16 bf16x4 __attribute__((ext_vector_type(4)));
typedef short short4v __attribute__((ext_vector_type(4)));
typedef float f32x4 __attribute__((ext_vector_type(4)));
typedef float f32x16 __attribute__((ext_vector_type(16)));
typedef unsigned uint2v __attribute__((ext_vector_type(2)));

union bfu { bf16_t b; u16 u; };
union trpair { short4v h[2]; bf16x8 v; };
union pfu { unsigned u[4]; bf16x8 v; };

#define QSCALE 0.18033688011112042f  /* 0.125 * log2(e) */

// hardware transpose read; "memory" clobber keeps it ordered vs ds_writes
#define TRD(dst, addr, OFF)                                                     \
  asm volatile("ds_read_b64_tr_b16 %0, %1 offset:" OFF                          \
               : "=v"(dst) : "v"(addr) : "memory")

__device__ __forceinline__ unsigned cvtpk(float a, float b) {
  unsigned r;
  asm("v_cvt_pk_bf16_f32 %0, %1, %2" : "=v"(r) : "v"(a), "v"(b));
  return r;
}
__device__ __forceinline__ uint2v plswap(unsigned a, unsigned b) {
  return __builtin_amdgcn_permlane32_swap(a, b, false, false);
}

// ---------------------------------------------------------------------------
// One-launch conversion: x, w_attn (QSCALE on q rows), w_proj -> bf16;
// b_attn -> scaled f32 bias.
// ---------------------------------------------------------------------------
__device__ __forceinline__ void cvt8(const float* s, u16* d, size_t i, float f) {
  float4 a = *(const float4*)(s + i);
  float4 b = *(const float4*)(s + i + 4);
  bf16x8 v;
  v[0]=(bf16_t)(a.x*f); v[1]=(bf16_t)(a.y*f); v[2]=(bf16_t)(a.z*f); v[3]=(bf16_t)(a.w*f);
  v[4]=(bf16_t)(b.x*f); v[5]=(bf16_t)(b.y*f); v[6]=(bf16_t)(b.z*f); v[7]=(bf16_t)(b.w*f);
  *(bf16x8*)(d + i) = v;
}

__global__ __launch_bounds__(256) void cvt_all(
    const float* __restrict__ x, const float* __restrict__ w_attn,
    const float* __restrict__ w_proj, const float* __restrict__ b_attn,
    u16* __restrict__ xb, u16* __restrict__ wab, u16* __restrict__ wpb,
    float* __restrict__ sbias)
{
  const int blk = blockIdx.x;
  if (blk < 4096) {                       // x
    size_t i = ((size_t)blk * 256 + threadIdx.x) * 8;
    cvt8(x, xb, i, 1.0f);
  } else if (blk < 5632) {                // w_attn
    size_t i = ((size_t)(blk - 4096) * 256 + threadIdx.x) * 8;
    cvt8(w_attn, wab, i, (i < (size_t)Cc * Cc) ? QSCALE : 1.0f);
  } else if (blk < 6144) {                // w_proj
    size_t i = ((size_t)(blk - 5632) * 256 + threadIdx.x) * 8;
    cvt8(w_proj, wpb, i, 1.0f);
  } else {                                // b_attn -> sbias
    int i0 = (blk - 6144) * 2048 + threadIdx.x * 8;
#pragma unroll
    for (int j = 0; j < 8; ++j) {
      int i = i0 + j;
      if (i < NQKV) sbias[i] = b_attn[i] * ((i < Cc) ? QSCALE : 1.0f);
    }
  }
}

// ---------------------------------------------------------------------------
// GEMM NT, bf16 inputs, reg-staged with preload; BK=64 as two independent
// [128][40] sub-buffers per matrix (kd=0/1). Halves barrier-drain events vs
// the BK=32 r4 structure; per-sub-buffer read addressing identical to r4.
// Staging: thread parity selects sub-buffer; 64B contiguous global per thread.
// ---------------------------------------------------------------------------
template <int OUTBF16>
__global__ __launch_bounds__(256) void gemm_bf16(
    const u16* __restrict__ A, const u16* __restrict__ Bm,
    const float* __restrict__ bias, void* __restrict__ Cout,
    int M, int N, int K)
{
  __shared__ __attribute__((aligned(16))) u16 sa0[128][40];
  __shared__ __attribute__((aligned(16))) u16 sa1[128][40];
  __shared__ __attribute__((aligned(16))) u16 sb0[128][40];
  __shared__ __attribute__((aligned(16))) u16 sb1[128][40];

  const int tid  = threadIdx.x;
  const int lane = tid & 63;
  const int wid  = tid >> 6;
  const int wr   = (wid >> 1) * 64;
  const int wc   = (wid & 1) * 64;
  const int l15  = lane & 15;
  const int lh   = lane >> 4;
  const int bm   = blockIdx.x * 128;
  const int bn   = blockIdx.y * 128;

  f32x4 acc[4][4] = {};

  const int srow = tid >> 1;          // 0..127 (2 threads/row)
  const int half = tid & 1;           // 0 -> cols [0,32) (buf0), 1 -> [32,64) (buf1)

  const u16* pa = A  + (size_t)(bm + srow) * K + half * 32;
  const u16* pb = Bm + (size_t)(bn + srow) * K + half * 32;

  u16 (*dA)[40] = half ? sa1 : sa0;
  u16 (*dB)[40] = half ? sb1 : sb0;

  uint4 ar0 = ((const uint4*)pa)[0], ar1 = ((const uint4*)pa)[1],
        ar2 = ((const uint4*)pa)[2], ar3 = ((const uint4*)pa)[3];
  uint4 br0 = ((const uint4*)pb)[0], br1 = ((const uint4*)pb)[1],
        br2 = ((const uint4*)pb)[2], br3 = ((const uint4*)pb)[3];
  pa += 64; pb += 64;

  for (int k0 = 0; k0 < K; k0 += 64) {
    __syncthreads();
    *(uint4*)&dA[srow][0]  = ar0; *(uint4*)&dA[srow][8]  = ar1;
    *(uint4*)&dA[srow][16] = ar2; *(uint4*)&dA[srow][24] = ar3;
    *(uint4*)&dB[srow][0]  = br0; *(uint4*)&dB[srow][8]  = br1;
    *(uint4*)&dB[srow][16] = br2; *(uint4*)&dB[srow][24] = br3;
    __syncthreads();
    if (k0 + 64 < K) {
      ar0 = ((const uint4*)pa)[0]; ar1 = ((const uint4*)pa)[1];
      ar2 = ((const uint4*)pa)[2]; ar3 = ((const uint4*)pa)[3];
      br0 = ((const uint4*)pb)[0]; br1 = ((const uint4*)pb)[1];
      br2 = ((const uint4*)pb)[2]; br3 = ((const uint4*)pb)[3];
      pa += 64; pb += 64;
    }

    bf16x8 af[4], bfv[4];
    // kd = 0
#pragma unroll
    for (int mi = 0; mi < 4; mi++)
      af[mi] = *(const bf16x8*)&sa0[wr + mi*16 + l15][lh * 8];
#pragma unroll
    for (int ni = 0; ni < 4; ni++)
      bfv[ni] = *(const bf16x8*)&sb0[wc + ni*16 + l15][lh * 8];
#pragma unroll
    for (int mi = 0; mi < 4; mi++)
#pragma unroll
      for (int ni = 0; ni < 4; ni++)
        acc[mi][ni] = __builtin_amdgcn_mfma_f32_16x16x32_bf16(
            af[mi], bfv[ni], acc[mi][ni], 0, 0, 0);
    // kd = 1
#pragma unroll
    for (int mi = 0; mi < 4; mi++)
      af[mi] = *(const bf16x8*)&sa1[wr + mi*16 + l15][lh * 8];
#pragma unroll
    for (int ni = 0; ni < 4; ni++)
      bfv[ni] = *(const bf16x8*)&sb1[wc + ni*16 + l15][lh * 8];
#pragma unroll
    for (int mi = 0; mi < 4; mi++)
#pragma unroll
      for (int ni = 0; ni < 4; ni++)
        acc[mi][ni] = __builtin_amdgcn_mfma_f32_16x16x32_bf16(
            af[mi], bfv[ni], acc[mi][ni], 0, 0, 0);
  }

#pragma unroll
  for (int mi = 0; mi < 4; mi++) {
#pragma unroll
    for (int ni = 0; ni < 4; ni++) {
      const int col = bn + wc + ni*16 + l15;
      const float bs = bias[col];
#pragma unroll
      for (int r = 0; r < 4; r++) {
        const int row = bm + wr + mi*16 + lh*4 + r;
        const float val = acc[mi][ni][r] + bs;
        if (OUTBF16) {
          bfu cv; cv.b = (bf16_t)val;
          ((u16*)Cout)[(size_t)row * N + col] = cv.u;
        } else {
          ((float*)Cout)[(size_t)row * N + col] = val;
        }
      }
    }
  }
}

// ---------------------------------------------------------------------------
// Causal flash attention (r11 version — 81.7 us measured): 8-wave blocks,
// 256-row q-tiles paired {x,7-x}; 3-buffer K/V rotation, one barrier per
// tile; T15 qk-ahead; T12 in-register softmax; tr-read PV.
// ---------------------------------------------------------------------------
#define BUFU 9216   /* u16 per buffer */

__global__ __launch_bounds__(512) void attn_kernel(
    const u16* __restrict__ qkv, u16* __restrict__ y)
{
  __shared__ __attribute__((aligned(16))) u16 smem[3 * BUFU];  // 55.3 KB

  const int tid  = threadIdx.x;
  const int lane = tid & 63;
  const int w    = tid >> 6;          // 0..7
  const int l31  = lane & 31;
  const int hh   = lane >> 5;
  const int l15  = lane & 15;
  const int lh   = lane >> 4;
  const int bh   = blockIdx.y;
  const int b    = bh >> 4;
  const int head = bh & 15;

  const size_t rowbase = (size_t)b * Tt * NQKV;

  const int skey = tid >> 3;
  const int sp   = tid & 7;
  const u16* kbase = qkv + rowbase + 1024 + head*64 + sp*8;
  const u16* vbase = qkv + rowbase + 2048 + head*64 + sp*8;

  const unsigned smemB = (unsigned)(size_t)(&smem[0]);
  const unsigned trl = smemB
      + ((lh>>1)*8 + (l15>>2))*144 + (lh&1)*32 + (l15&3)*8;

  uint4 kr0, vr0;
#define LOADREGS(t) do {                                                        \
    kr0 = *(const uint4*)(kbase + (size_t)((t)*64 + skey) * NQKV);              \
    vr0 = *(const uint4*)(vbase + (size_t)((t)*64 + skey) * NQKV);              \
  } while (0)
#define STAGEB(bofs) do {                                                       \
    *(uint4*)&smem[(bofs) + skey*72 + sp*8]        = kr0;                       \
    *(uint4*)&smem[(bofs) + 4608 + skey*72 + sp*8] = vr0;                       \
  } while (0)

  for (int half = 0; half < 2; ++half) {
    const int qx    = half ? (7 - (int)blockIdx.x) : (int)blockIdx.x;
    const int qbase = qx * 256;
    const int qw    = qbase + w * 32;
    const int qi    = qw + l31;
    const int ktiles = 4*qx + 4;

    bf16x8 qfrag[4];
#pragma unroll
    for (int m = 0; m < 4; ++m)
      qfrag[m] = *(const bf16x8*)(qkv + rowbase + (size_t)qi * NQKV
                                  + head*64 + m*16 + hh*8);

    f32x16 o0 = {}, o1 = {};
    float m_run = -1e30f, l_part = 0.0f;
    f32x16 sA0, sA1, sB0, sB1;

    auto qk = [&](f32x16& t0, f32x16& t1, int kofs, int kb0) {
      f32x16 a0 = {}, a1 = {};
      __builtin_amdgcn_s_setprio(1);
#pragma unroll
      for (int m = 0; m < 4; ++m) {
        const int co = m*16 + hh*8;
        bf16x8 k0 = *(const bf16x8*)&smem[kofs + l31*72 + co];
        bf16x8 k1 = *(const bf16x8*)&smem[kofs + (32 + l31)*72 + co];
        a0 = __builtin_amdgcn_mfma_f32_32x32x16_bf16(k0, qfrag[m], a0, 0,0,0);
        a1 = __builtin_amdgcn_mfma_f32_32x32x16_bf16(k1, qfrag[m], a1, 0,0,0);
      }
      __builtin_amdgcn_s_setprio(0);
      if (kb0 + 63 > qw) {
#pragma unroll
        for (int r = 0; r < 16; ++r) {
          const int crow = (r&3) + 8*(r>>2) + 4*hh;
          if (kb0 + crow > qi)      a0[r] = -1e30f;
          if (kb0 + 32 + crow > qi) a1[r] = -1e30f;
        }
      }
      t0 = a0; t1 = a1;
    };

    auto smpv = [&](f32x16& s0, f32x16& s1, int bofs) {
      float mx[8];
#pragma unroll
      for (int i = 0; i < 8; ++i)
        mx[i] = fmaxf(fmaxf(s0[i], s0[i+8]), fmaxf(s1[i], s1[i+8]));
#pragma unroll
      for (int i = 0; i < 4; ++i) mx[i] = fmaxf(mx[i], mx[i+4]);
      mx[0] = fmaxf(mx[0], mx[2]); mx[1] = fmaxf(mx[1], mx[3]);
      float rm = fmaxf(mx[0], mx[1]);
      {
        uint2v t = plswap(__float_as_uint(rm), __float_as_uint(rm));
        rm = fmaxf(__uint_as_float(t[0]), __uint_as_float(t[1]));
      }
      if (__any(rm > m_run + 8.0f)) {
        const float mn = fmaxf(m_run, rm);
        const float al = exp2f(m_run - mn);
        m_run = mn; l_part *= al;
#pragma unroll
        for (int r = 0; r < 16; ++r) { o0[r] *= al; o1[r] *= al; }
      }

      pfu pf0, pf1, pf2, pf3;
      float lp0 = 0.f, lp1 = 0.f, lp2 = 0.f, lp3 = 0.f;
      {
        float pe[16];
#pragma unroll
        for (int r = 0; r < 16; ++r) pe[r] = exp2f(s0[r] - m_run);
#pragma unroll
        for (int r = 0; r < 4; ++r) {
          lp0 += pe[r]; lp1 += pe[4+r]; lp2 += pe[8+r]; lp3 += pe[12+r];
        }
        unsigned a0 = cvtpk(pe[0],pe[1]),  a1 = cvtpk(pe[2],pe[3]);
        unsigned a2 = cvtpk(pe[4],pe[5]),  a3 = cvtpk(pe[6],pe[7]);
        uint2v x1 = plswap(a0, a2), x2 = plswap(a1, a3);
        pf0.u[0]=x1[0]; pf0.u[1]=x2[0]; pf0.u[2]=x1[1]; pf0.u[3]=x2[1];
        unsigned b0 = cvtpk(pe[8],pe[9]),  b1 = cvtpk(pe[10],pe[11]);
        unsigned b2 = cvtpk(pe[12],pe[13]), b3 = cvtpk(pe[14],pe[15]);
        uint2v x3 = plswap(b0, b2), x4 = plswap(b1, b3);
        pf1.u[0]=x3[0]; pf1.u[1]=x4[0]; pf1.u[2]=x3[1]; pf1.u[3]=x4[1];
      }
      {
        float pe[16];
#pragma unroll
        for (int r = 0; r < 16; ++r) pe[r] = exp2f(s1[r] - m_run);
#pragma unroll
        for (int r = 0; r < 4; ++r) {
          lp0 += pe[r]; lp1 += pe[4+r]; lp2 += pe[8+r]; lp3 += pe[12+r];
        }
        unsigned a0 = cvtpk(pe[0],pe[1]),  a1 = cvtpk(pe[2],pe[3]);
        unsigned a2 = cvtpk(pe[4],pe[5]),  a3 = cvtpk(pe[6],pe[7]);
        uint2v x1 = plswap(a0, a2), x2 = plswap(a1, a3);
        pf2.u[0]=x1[0]; pf2.u[1]=x2[0]; pf2.u[2]=x1[1]; pf2.u[3]=x2[1];
        unsigned b0 = cvtpk(pe[8],pe[9]),  b1 = cvtpk(pe[10],pe[11]);
        unsigned b2 = cvtpk(pe[12],pe[13]), b3 = cvtpk(pe[14],pe[15]);
        uint2v x3 = plswap(b0, b2), x4 = plswap(b1, b3);
        pf3.u[0]=x3[0]; pf3.u[1]=x4[0]; pf3.u[2]=x3[1]; pf3.u[3]=x4[1];
      }
      l_part += (lp0 + lp1) + (lp2 + lp3);

      const unsigned va = trl + (unsigned)(bofs*2 + 9216);
      short4v ta0,tb0,ta1,tb1,ta2,tb2,ta3,tb3,ta4,tb4,ta5,tb5,ta6,tb6,ta7,tb7;
      TRD(ta0, va, "0");    TRD(tb0, va, "576");
      TRD(ta1, va, "64");   TRD(tb1, va, "640");
      TRD(ta2, va, "2304"); TRD(tb2, va, "2880");
      TRD(ta3, va, "2368"); TRD(tb3, va, "2944");
      TRD(ta4, va, "4608"); TRD(tb4, va, "5184");
      TRD(ta5, va, "4672"); TRD(tb5, va, "5248");
      TRD(ta6, va, "6912"); TRD(tb6, va, "7488");
      TRD(ta7, va, "6976"); TRD(tb7, va, "7552");
      asm volatile("s_waitcnt lgkmcnt(0)" ::: "memory");
      __builtin_amdgcn_sched_barrier(0);
      trpair v00,v01,v10,v11,v20,v21,v30,v31;
      v00.h[0]=ta0; v00.h[1]=tb0;  v01.h[0]=ta1; v01.h[1]=tb1;
      v10.h[0]=ta2; v10.h[1]=tb2;  v11.h[0]=ta3; v11.h[1]=tb3;
      v20.h[0]=ta4; v20.h[1]=tb4;  v21.h[0]=ta5; v21.h[1]=tb5;
      v30.h[0]=ta6; v30.h[1]=tb6;  v31.h[0]=ta7; v31.h[1]=tb7;
      __builtin_amdgcn_s_setprio(1);
      o0 = __builtin_amdgcn_mfma_f32_32x32x16_bf16(v00.v, pf0.v, o0, 0,0,0);
      o1 = __builtin_amdgcn_mfma_f32_32x32x16_bf16(v01.v, pf0.v, o1, 0,0,0);
      o0 = __builtin_amdgcn_mfma_f32_32x32x16_bf16(v10.v, pf1.v, o0, 0,0,0);
      o1 = __builtin_amdgcn_mfma_f32_32x32x16_bf16(v11.v, pf1.v, o1, 0,0,0);
      o0 = __builtin_amdgcn_mfma_f32_32x32x16_bf16(v20.v, pf2.v, o0, 0,0,0);
      o1 = __builtin_amdgcn_mfma_f32_32x32x16_bf16(v21.v, pf2.v, o1, 0,0,0);
      o0 = __builtin_amdgcn_mfma_f32_32x32x16_bf16(v30.v, pf3.v, o0, 0,0,0);
      o1 = __builtin_amdgcn_mfma_f32_32x32x16_bf16(v31.v, pf3.v, o1, 0,0,0);
      __builtin_amdgcn_s_setprio(0);
    };

    LOADREGS(0);
    __syncthreads();
    STAGEB(0);
    LOADREGS(1);
    __syncthreads();
    qk(sA0, sA1, 0, 0);
    STAGEB(BUFU);
    LOADREGS(2);

    int cofs = 0, nofs = BUFU, fofs = 2*BUFU;

    for (int kt = 0; kt < ktiles; kt += 2) {
      __syncthreads();
      if ((kt+1)*64 <= qw + 31) qk(sB0, sB1, nofs, (kt+1)*64);
      if (kt*64 <= qw + 31)     smpv(sA0, sA1, cofs);
      if (kt + 2 < ktiles) {
        STAGEB(fofs);
        if (kt + 3 < ktiles) LOADREGS(kt + 3);
      }
      { int t = cofs; cofs = nofs; nofs = fofs; fofs = t; }

      __syncthreads();
      if ((kt+2) < ktiles && (kt+2)*64 <= qw + 31) qk(sA0, sA1, nofs, (kt+2)*64);
      if ((kt+1)*64 <= qw + 31) smpv(sB0, sB1, cofs);
      if (kt + 3 < ktiles) {
        STAGEB(fofs);
        if (kt + 4 < ktiles) LOADREGS(kt + 4);
      }
      { int t = cofs; cofs = nofs; nofs = fofs; fofs = t; }
    }

    {
      uint2v t = plswap(__float_as_uint(l_part), __float_as_uint(l_part));
      l_part = __uint_as_float(t[0]) + __uint_as_float(t[1]);
    }
    const float inv = 1.0f / l_part;

    __syncthreads();
#pragma unroll
    for (int k4 = 0; k4 < 4; ++k4) {
      bf16x4 pa, pb;
#pragma unroll
      for (int j = 0; j < 4; ++j) {
        pa[j] = (bf16_t)(o0[4*k4 + j] * inv);
        pb[j] = (bf16_t)(o1[4*k4 + j] * inv);
      }
      *(bf16x4*)&smem[w*2304 + l31*72 +      8*k4 + 4*hh] = pa;
      *(bf16x4*)&smem[w*2304 + l31*72 + 32 + 8*k4 + 4*hh] = pb;
    }
    u16* yp = y + ((size_t)(b*Tt + qi)) * Cc + head*64;
#pragma unroll
    for (int p = 0; p < 4; ++p) {
      bf16x8 row = *(const bf16x8*)&smem[w*2304 + l31*72 + p*16 + hh*8];
      *(bf16x8*)(yp + p*16 + hh*8) = row;
    }
  }
#undef LOADREGS
#undef STAGEB
}

// ---------------------------------------------------------------------------
extern "C" void kernel_launch(void* const* d_in, const int* in_sizes, int n_in,
                              void* d_out, int out_size, void* d_ws, size_t ws_size,
                              hipStream_t stream) {
  const float* x      = (const float*)d_in[0];
  const float* w_attn = (const float*)d_in[1];
  const float* b_attn = (const float*)d_in[2];
  const float* w_proj = (const float*)d_in[3];
  const float* b_proj = (const float*)d_in[4];
  float* out = (float*)d_out;

  char* ws = (char*)d_ws;
  u16*   xb    = (u16*)(ws + 0);          // 16 MB
  u16*   wab   = (u16*)(ws + 16777216);   // 6 MB
  u16*   wpb   = (u16*)(ws + 23068672);   // 2 MB
  u16*   qkvb  = (u16*)(ws + 25165824);   // 48 MB
  u16*   yb    = (u16*)(ws + 75497472);   // 16 MB
  float* sbias = (float*)(ws + 92274688); // 12 KB

  // single-launch conversion (x, w_attn+QSCALE, w_proj, b_attn)
  cvt_all<<<6146, 256, 0, stream>>>(x, w_attn, w_proj, b_attn,
                                    xb, wab, wpb, sbias);

  // 1) QKV projection (bf16 out, q pre-scaled) — BK=64 variant
  gemm_bf16<1><<<dim3(Mtot/128, NQKV/128), 256, 0, stream>>>(
      xb, wab, sbias, (void*)qkvb, Mtot, NQKV, Cc);

  // 2) causal attention (bf16 y)
  attn_kernel<<<dim3(4, Bb*Hh), 512, 0, stream>>>(qkvb, yb);

  // 3) output projection (f32 out) — BK=64 variant
  gemm_bf16<0><<<dim3(Mtot/128, Cc/128), 256, 0, stream>>>(
      yb, wpb, b_proj, (void*)out, Mtot, Cc, Cc);
}